// Round 5
// baseline (1198.597 us; speedup 1.0000x reference)
//
#include <hip/hip_runtime.h>

typedef unsigned int u32;
typedef unsigned short u16;
typedef unsigned long long u64;
typedef short s16x8 __attribute__((ext_vector_type(8)));
typedef float f32x4 __attribute__((ext_vector_type(4)));

#define SENTW 0xFFFFFFFFu
#define GRU_WGS 32

// ---------- helpers ----------
__device__ __forceinline__ u16 f2bf(float f) {
  u32 u = __float_as_uint(f);
  u32 r = (u + 0x7fffu + ((u >> 16) & 1u)) >> 16;  // RNE
  return (u16)r;
}

// 4x16B L1/L2-bypassing loads, single wait (early-clobber: dests must not alias addrs)
__device__ __forceinline__ void load4_bypass(const u16* p0, const u16* p1,
                                             const u16* p2, const u16* p3,
                                             uint4& r0, uint4& r1, uint4& r2, uint4& r3) {
  asm volatile(
      "global_load_dwordx4 %0, %4, off sc0 sc1\n\t"
      "global_load_dwordx4 %1, %5, off sc0 sc1\n\t"
      "global_load_dwordx4 %2, %6, off sc0 sc1\n\t"
      "global_load_dwordx4 %3, %7, off sc0 sc1\n\t"
      "s_waitcnt vmcnt(0)"
      : "=&v"(r0), "=&v"(r1), "=&v"(r2), "=&v"(r3)
      : "v"(p0), "v"(p1), "v"(p2), "v"(p3)
      : "memory");
}

__device__ __forceinline__ bool any_sent(uint4 v) {
  return v.x == SENTW || v.y == SENTW || v.z == SENTW || v.w == SENTW;
}

// ---------- fp32 -> bf16 convert (vectorized) ----------
__global__ __launch_bounds__(256) void cvt_bf16_kernel(const float* __restrict__ src,
                                                       u16* __restrict__ dst, int n4) {
  int i = blockIdx.x * 256 + threadIdx.x;
  if (i >= n4) return;
  float4 v = reinterpret_cast<const float4*>(src)[i];
  u32 lo = (u32)f2bf(v.x) | ((u32)f2bf(v.y) << 16);
  u32 hi = (u32)f2bf(v.z) | ((u32)f2bf(v.w) << 16);
  reinterpret_cast<uint2*>(dst)[i] = make_uint2(lo, hi);
}

// ---------- build x = [emb[tok] ; thought] as bf16, rows m = s*16+b, K=1024 ----------
__global__ __launch_bounds__(128) void build_x_kernel(const int* __restrict__ tseq,
                                                      const float* __restrict__ emb,
                                                      const float* __restrict__ thought,
                                                      u16* __restrict__ x) {
  int m = blockIdx.x;  // m = s*16 + b
  int s = m >> 4, b = m & 15;
  int tid = threadIdx.x;
  int k = tid * 8;
  const float* src;
  if (k < 512) src = emb + (size_t)tseq[b * 64 + s] * 512 + k;
  else         src = thought + b * 512 + (k - 512);
  float4 v0 = reinterpret_cast<const float4*>(src)[0];
  float4 v1 = reinterpret_cast<const float4*>(src)[1];
  uint4 o;
  o.x = (u32)f2bf(v0.x) | ((u32)f2bf(v0.y) << 16);
  o.y = (u32)f2bf(v0.z) | ((u32)f2bf(v0.w) << 16);
  o.z = (u32)f2bf(v1.x) | ((u32)f2bf(v1.y) << 16);
  o.w = (u32)f2bf(v1.z) | ((u32)f2bf(v1.w) << 16);
  *reinterpret_cast<uint4*>(x + (size_t)m * 1024 + k) = o;
}

// ---------- bf16 MFMA GEMM (single M-tile) for gi ----------
__global__ __launch_bounds__(256) void gemm_bt_kernel(const u16* __restrict__ A,
                                                      const u16* __restrict__ Bm,
                                                      const float* __restrict__ bias,
                                                      float* __restrict__ C,
                                                      int N_, int K_) {
  __shared__ u16 sA[128 * 40];
  __shared__ u16 sB[128 * 40];
  int nb = blockIdx.x, mb = blockIdx.y;
  int m0 = mb * 128, n0 = nb * 128;
  int tid = threadIdx.x;
  int wave = tid >> 6, lane = tid & 63;
  int wm = wave >> 1, wn = wave & 1;
  int l16 = lane & 15, quad = lane >> 4;
  int srow = tid >> 1, shalf = tid & 1;
  const u16* gA = A + (size_t)(m0 + srow) * K_ + shalf * 16;
  const u16* gB = Bm + (size_t)(n0 + srow) * K_ + shalf * 16;
  u16* lA = &sA[srow * 40 + shalf * 16];
  u16* lB = &sB[srow * 40 + shalf * 16];
  f32x4 acc[4][4];
  for (int i = 0; i < 4; ++i)
    for (int j = 0; j < 4; ++j) acc[i][j] = (f32x4){0.f, 0.f, 0.f, 0.f};

  for (int k0 = 0; k0 < K_; k0 += 32) {
    uint4 a0 = *reinterpret_cast<const uint4*>(gA + k0);
    uint4 a1 = *reinterpret_cast<const uint4*>(gA + k0 + 8);
    uint4 b0 = *reinterpret_cast<const uint4*>(gB + k0);
    uint4 b1 = *reinterpret_cast<const uint4*>(gB + k0 + 8);
    __syncthreads();
    *reinterpret_cast<uint4*>(lA) = a0;
    *reinterpret_cast<uint4*>(lA + 8) = a1;
    *reinterpret_cast<uint4*>(lB) = b0;
    *reinterpret_cast<uint4*>(lB + 8) = b1;
    __syncthreads();
    s16x8 af[4], bfr[4];
    for (int mt = 0; mt < 4; ++mt)
      af[mt] = *reinterpret_cast<const s16x8*>(&sA[(wm * 64 + mt * 16 + l16) * 40 + quad * 8]);
    for (int nt = 0; nt < 4; ++nt)
      bfr[nt] = *reinterpret_cast<const s16x8*>(&sB[(wn * 64 + nt * 16 + l16) * 40 + quad * 8]);
    for (int mt = 0; mt < 4; ++mt)
      for (int nt = 0; nt < 4; ++nt)
        acc[mt][nt] = __builtin_amdgcn_mfma_f32_16x16x32_bf16(af[mt], bfr[nt], acc[mt][nt], 0, 0, 0);
  }
  int rbase = wm * 64 + quad * 4;
  int cbase = n0 + wn * 64 + l16;
  for (int nt = 0; nt < 4; ++nt) {
    float bv = bias[cbase + nt * 16];
    for (int mt = 0; mt < 4; ++mt)
      for (int r = 0; r < 4; ++r) acc[mt][nt][r] += bv;
  }
  for (int mt = 0; mt < 4; ++mt)
    for (int r = 0; r < 4; ++r) {
      int row = m0 + rbase + mt * 16 + r;
      for (int nt = 0; nt < 4; ++nt)
        C[(size_t)row * N_ + cbase + nt * 16] = acc[mt][nt][r];
    }
}

// ---------- logits GEMM: 2 M-tiles/WG, A = hpub with row remap, LSE partials ----------
// logical row m = b*64+t ; hpub row = t*16+b = ((m&63)<<4) + (m>>6)
__global__ __launch_bounds__(256, 2) void gemm_logits_kernel(const u16* __restrict__ A,
                                                             const u16* __restrict__ Bm,
                                                             const float* __restrict__ bias,
                                                             float* __restrict__ C,
                                                             int N_, int K_,
                                                             float* __restrict__ partials,
                                                             int nnb) {
  __shared__ u16 sA[2][128 * 40];
  __shared__ u16 sB[128 * 40];
  __shared__ float pm[2][128];
  __shared__ float ps[2][128];
  int nb = blockIdx.x, mb = blockIdx.y;
  int m0 = mb * 256, n0 = nb * 128;
  int tid = threadIdx.x;
  int wave = tid >> 6, lane = tid & 63;
  int wm = wave >> 1, wn = wave & 1;
  int l16 = lane & 15, quad = lane >> 4;
  int srow = tid >> 1, shalf = tid & 1;
  int am0 = m0 + srow, am1 = m0 + 128 + srow;
  int ar0 = ((am0 & 63) << 4) + (am0 >> 6);
  int ar1 = ((am1 & 63) << 4) + (am1 >> 6);
  const u16* gA0 = A + (size_t)ar0 * K_ + shalf * 16;
  const u16* gA1 = A + (size_t)ar1 * K_ + shalf * 16;
  const u16* gB = Bm + (size_t)(n0 + srow) * K_ + shalf * 16;
  u16* lA0 = &sA[0][srow * 40 + shalf * 16];
  u16* lA1 = &sA[1][srow * 40 + shalf * 16];
  u16* lB = &sB[srow * 40 + shalf * 16];
  f32x4 acc[2][4][4];
  for (int tt = 0; tt < 2; ++tt)
    for (int i = 0; i < 4; ++i)
      for (int j = 0; j < 4; ++j) acc[tt][i][j] = (f32x4){0.f, 0.f, 0.f, 0.f};

  for (int k0 = 0; k0 < K_; k0 += 32) {
    uint4 a00 = *reinterpret_cast<const uint4*>(gA0 + k0);
    uint4 a01 = *reinterpret_cast<const uint4*>(gA0 + k0 + 8);
    uint4 a10 = *reinterpret_cast<const uint4*>(gA1 + k0);
    uint4 a11 = *reinterpret_cast<const uint4*>(gA1 + k0 + 8);
    uint4 b0 = *reinterpret_cast<const uint4*>(gB + k0);
    uint4 b1 = *reinterpret_cast<const uint4*>(gB + k0 + 8);
    __syncthreads();
    *reinterpret_cast<uint4*>(lA0) = a00;
    *reinterpret_cast<uint4*>(lA0 + 8) = a01;
    *reinterpret_cast<uint4*>(lA1) = a10;
    *reinterpret_cast<uint4*>(lA1 + 8) = a11;
    *reinterpret_cast<uint4*>(lB) = b0;
    *reinterpret_cast<uint4*>(lB + 8) = b1;
    __syncthreads();
    s16x8 af[2][4], bfr[4];
    for (int tt = 0; tt < 2; ++tt)
      for (int mt = 0; mt < 4; ++mt)
        af[tt][mt] =
            *reinterpret_cast<const s16x8*>(&sA[tt][(wm * 64 + mt * 16 + l16) * 40 + quad * 8]);
    for (int nt = 0; nt < 4; ++nt)
      bfr[nt] = *reinterpret_cast<const s16x8*>(&sB[(wn * 64 + nt * 16 + l16) * 40 + quad * 8]);
    for (int tt = 0; tt < 2; ++tt)
      for (int mt = 0; mt < 4; ++mt)
        for (int nt = 0; nt < 4; ++nt)
          acc[tt][mt][nt] =
              __builtin_amdgcn_mfma_f32_16x16x32_bf16(af[tt][mt], bfr[nt], acc[tt][mt][nt], 0, 0, 0);
  }

  int rbase = wm * 64 + quad * 4;
  int cbase = n0 + wn * 64 + l16;
  float bv[4];
  for (int nt = 0; nt < 4; ++nt) bv[nt] = bias[cbase + nt * 16];
  for (int tt = 0; tt < 2; ++tt) {
    int mt0 = m0 + tt * 128;
    for (int nt = 0; nt < 4; ++nt)
      for (int mt = 0; mt < 4; ++mt)
        for (int r = 0; r < 4; ++r) acc[tt][mt][nt][r] += bv[nt];
    for (int mt = 0; mt < 4; ++mt)
      for (int r = 0; r < 4; ++r) {
        int row = mt0 + rbase + mt * 16 + r;
        for (int nt = 0; nt < 4; ++nt)
          C[(size_t)row * N_ + cbase + nt * 16] = acc[tt][mt][nt][r];
      }
    for (int mt = 0; mt < 4; ++mt)
      for (int r = 0; r < 4; ++r) {
        float mx = acc[tt][mt][0][r];
        for (int nt = 1; nt < 4; ++nt) mx = fmaxf(mx, acc[tt][mt][nt][r]);
        for (int d = 1; d < 16; d <<= 1) mx = fmaxf(mx, __shfl_xor(mx, d));
        float sm = 0.f;
        for (int nt = 0; nt < 4; ++nt) sm += __expf(acc[tt][mt][nt][r] - mx);
        for (int d = 1; d < 16; d <<= 1) sm += __shfl_xor(sm, d);
        if (l16 == 0) {
          int rr = wm * 64 + mt * 16 + quad * 4 + r;
          pm[wn][rr] = mx;
          ps[wn][rr] = sm;
        }
      }
    __syncthreads();
    if (tid < 128) {
      float m1 = pm[0][tid], m2 = pm[1][tid];
      float s1 = ps[0][tid], s2 = ps[1][tid];
      float Mx = fmaxf(m1, m2);
      float Sx = s1 * __expf(m1 - Mx) + s2 * __expf(m2 - Mx);
      float* p = partials + ((size_t)(mt0 + tid) * nnb + nb) * 2;
      p[0] = Mx;
      p[1] = Sx;
    }
    __syncthreads();
  }
}

// ---------- GRU recurrence: 32 MFMA WGs + spare WGs convert W_out ----------
// WG g owns h-indices g*16..g*16+15 (all 16 batches). Per step:
//   read h_{t-1}[16][512] bf16 from hpub (sentinel-validated bypass loads),
//   gh[3 gates][16b][16h] = H x W_slice^T via mfma (waves 0-2, 16 mfma each),
//   gates elementwise (thread = (b,i), h_prev in register), publish bf16.
// hpub[t][b][512] bf16; 0xFFFF sentinel (NaN, unreachable). Publish via 8B
// relaxed agent-scope atomic stores; readers validate EVERY dword (a dword is
// two bf16; 0xFFFFFFFF requires both = NaN, impossible for real h).
__global__ __launch_bounds__(256) void gru_fused_kernel(
    const float* __restrict__ gi, const float* __restrict__ W_hh,
    const float* __restrict__ b_hh, const float* __restrict__ hidden,
    u16* __restrict__ hpub, float* __restrict__ hlast,
    const float* __restrict__ W_out, u16* __restrict__ wout_bf, int cvt_n4) {
  int wg = blockIdx.x;
  int tid = threadIdx.x;
  if (wg >= GRU_WGS) {
    // spare WGs: convert W_out fp32->bf16 (grid-stride)
    int idx = (wg - GRU_WGS) * 256 + tid;
    int stride = (gridDim.x - GRU_WGS) * 256;
    for (int i = idx; i < cvt_n4; i += stride) {
      float4 v = reinterpret_cast<const float4*>(W_out)[i];
      u32 lo = (u32)f2bf(v.x) | ((u32)f2bf(v.y) << 16);
      u32 hi = (u32)f2bf(v.z) | ((u32)f2bf(v.w) << 16);
      reinterpret_cast<uint2*>(wout_bf)[i] = make_uint2(lo, hi);
    }
    return;
  }
  __shared__ u16 sW[48 * 520];       // W slice bf16, row stride 520
  __shared__ u16 hbf[16 * 520];      // h_{t-1} bf16 [b][k]
  __shared__ float gh_s[3][16][17];  // [gate][batch][hidx], padded
  __shared__ u16 pub_s[256];         // staging for publish
  int g = wg;
  // load W slice: local row lr -> global row (lr>>4)*512 + g*16 + (lr&15)
  for (int lr = 0; lr < 48; ++lr) {
    int grow = (lr >> 4) * 512 + g * 16 + (lr & 15);
    float2 v = reinterpret_cast<const float2*>(W_hh + (size_t)grow * 512)[tid];
    u16* dw = &sW[lr * 520 + tid * 2];
    dw[0] = f2bf(v.x);
    dw[1] = f2bf(v.y);
  }
  int b = tid >> 4, i = tid & 15;  // gate-combine mapping
  int j = g * 16 + i;
  float h_prev = hidden[b * 512 + j];
  float bh_r = b_hh[j], bh_z = b_hh[512 + j], bh_n = b_hh[1024 + j];
  int wave = tid >> 6, lane = tid & 63, l16 = lane & 15, quad = lane >> 4;
  // consumer read mapping: (bb, k0) chunk of 32 u16 = 64B
  int bb = tid & 15, k0 = (tid >> 4) * 32;
  u16* hdst = &hbf[bb * 520 + k0];
  // publisher mapping (tid<64): batch pb, 8B part q
  int pb = tid >> 2, pq = tid & 3;

  for (int t = 0; t < 64; ++t) {
    // gi loads for this thread's (b, gates, j) — independent of h, issue early
    size_t gib = ((size_t)t * 16 + b) * 1536;
    float gi_r = gi[gib + j], gi_z = gi[gib + 512 + j], gi_n = gi[gib + 1024 + j];
    if (t == 0) {
      for (int q = tid; q < 2048; q += 256) {  // 16*512/4 float4s of hidden
        int qb = q >> 7, qk = (q & 127) * 4;
        float4 v = reinterpret_cast<const float4*>(hidden)[q];
        u16* d = &hbf[qb * 520 + qk];
        d[0] = f2bf(v.x); d[1] = f2bf(v.y); d[2] = f2bf(v.z); d[3] = f2bf(v.w);
      }
    } else {
      const u16* p = hpub + (size_t)(t - 1) * 8192 + bb * 512 + k0;
      uint4 r0, r1, r2, r3;
      load4_bypass(p, p + 8, p + 16, p + 24, r0, r1, r2, r3);
      while (any_sent(r0) || any_sent(r1) || any_sent(r2) || any_sent(r3)) {
        __builtin_amdgcn_s_sleep(1);
        load4_bypass(p, p + 8, p + 16, p + 24, r0, r1, r2, r3);
      }
      *reinterpret_cast<uint4*>(hdst + 0) = r0;
      *reinterpret_cast<uint4*>(hdst + 8) = r1;
      *reinterpret_cast<uint4*>(hdst + 16) = r2;
      *reinterpret_cast<uint4*>(hdst + 24) = r3;
    }
    __syncthreads();
    if (wave < 3) {
      f32x4 acc = (f32x4){0.f, 0.f, 0.f, 0.f};
      const u16* wrow = &sW[(wave * 16 + l16) * 520];
      const u16* arow = &hbf[l16 * 520];
      for (int kk = 0; kk < 16; ++kk) {
        s16x8 af = *reinterpret_cast<const s16x8*>(arow + kk * 32 + quad * 8);
        s16x8 bf = *reinterpret_cast<const s16x8*>(wrow + kk * 32 + quad * 8);
        acc = __builtin_amdgcn_mfma_f32_16x16x32_bf16(af, bf, acc, 0, 0, 0);
      }
      for (int r = 0; r < 4; ++r) gh_s[wave][quad * 4 + r][l16] = acc[r];
    }
    __syncthreads();
    {
      float ghr = gh_s[0][b][i] + bh_r;
      float ghz = gh_s[1][b][i] + bh_z;
      float ghn = gh_s[2][b][i] + bh_n;
      float r = 1.f / (1.f + __expf(-(gi_r + ghr)));
      float z = 1.f / (1.f + __expf(-(gi_z + ghz)));
      float n = tanhf(gi_n + r * ghn);
      float hv = (1.f - z) * n + z * h_prev;
      h_prev = hv;
      pub_s[b * 16 + i] = f2bf(hv);
    }
    __syncthreads();
    if (tid < 64) {
      u64 v = *reinterpret_cast<const u64*>(&pub_s[pb * 16 + pq * 4]);
      u64* dst = reinterpret_cast<u64*>(hpub + (size_t)t * 8192 + pb * 512 + g * 16 + pq * 4);
      __hip_atomic_store(dst, v, __ATOMIC_RELAXED, __HIP_MEMORY_SCOPE_AGENT);
    }
    __syncthreads();
  }
  hlast[b * 512 + j] = h_prev;
}

// ---------- combine per-row LSE partials ----------
__global__ __launch_bounds__(64) void lse_combine_kernel(const float* __restrict__ partials,
                                                         float* __restrict__ lse, int nnb) {
  int row = blockIdx.x;
  int lane = threadIdx.x;
  float M = -INFINITY, S = 0.f;
  for (int i = lane; i < nnb; i += 64) {
    const float* p = partials + ((size_t)row * nnb + i) * 2;
    float m2 = p[0], s2 = p[1];
    if (m2 > M) { float tt = M; M = m2; m2 = tt; tt = S; S = s2; s2 = tt; }
    if (s2 > 0.f) S += s2 * __expf(m2 - M);
  }
  for (int d = 1; d < 64; d <<= 1) {
    float m2 = __shfl_xor(M, d), s2 = __shfl_xor(S, d);
    if (m2 > M) { float tt = M; M = m2; m2 = tt; tt = S; S = s2; s2 = tt; }
    if (s2 > 0.f) S += s2 * __expf(m2 - M);
  }
  if (lane == 0) lse[row] = M + logf(S);
}

// ---------- logp = logits - lse[row] ----------
__global__ __launch_bounds__(256) void sub_lse_kernel(float* __restrict__ out,
                                                      const float* __restrict__ lse) {
  int i = blockIdx.x * 256 + threadIdx.x;  // 8000 float4s per row
  int row = i / 8000;
  float l = lse[row];
  float4 v = reinterpret_cast<float4*>(out)[i];
  v.x -= l; v.y -= l; v.z -= l; v.w -= l;
  reinterpret_cast<float4*>(out)[i] = v;
}

extern "C" void kernel_launch(void* const* d_in, const int* in_sizes, int n_in,
                              void* d_out, int out_size, void* d_ws, size_t ws_size,
                              hipStream_t stream) {
  const int* tseq = (const int*)d_in[0];
  const float* thought = (const float*)d_in[1];
  const float* hidden = (const float*)d_in[2];
  const float* emb = (const float*)d_in[3];
  const float* W_ih = (const float*)d_in[4];
  const float* W_hh = (const float*)d_in[5];
  const float* b_ih = (const float*)d_in[6];
  const float* b_hh = (const float*)d_in[7];
  const float* W_out = (const float*)d_in[8];
  const float* b_out = (const float*)d_in[9];
  float* out = (float*)d_out;

  char* ws = (char*)d_ws;
  size_t off = 0;
  auto alloc = [&](size_t bytes) {
    void* p = ws + off;
    off = (off + bytes + 255) & ~(size_t)255;
    return p;
  };
  u16* wout_bf = (u16*)alloc((size_t)32000 * 512 * 2);
  u16* wih_bf  = (u16*)alloc((size_t)1536 * 1024 * 2);
  u16* x_bf    = (u16*)alloc((size_t)1024 * 1024 * 2);
  float* gi    = (float*)alloc((size_t)1024 * 1536 * 4);
  u16* hpub    = (u16*)alloc((size_t)64 * 16 * 512 * 2);
  float* partials = (float*)alloc((size_t)1024 * 250 * 2 * 4);
  float* lse   = (float*)alloc((size_t)1024 * 4);
  (void)ws_size; (void)in_sizes; (void)n_in; (void)out_size;

  (void)hipMemsetAsync(hpub, 0xFF, (size_t)64 * 16 * 512 * 2, stream);  // bf16 NaN sentinel
  cvt_bf16_kernel<<<1536, 256, 0, stream>>>(W_ih, wih_bf, 393216);
  build_x_kernel<<<1024, 128, 0, stream>>>(tseq, emb, thought, x_bf);
  gemm_bt_kernel<<<dim3(12, 8), 256, 0, stream>>>(x_bf, wih_bf, b_ih, gi, 1536, 1024);
  gru_fused_kernel<<<256, 256, 0, stream>>>(gi, W_hh, b_hh, hidden, hpub,
                                            out + 32768000, W_out, wout_bf, 4096000);
  gemm_logits_kernel<<<dim3(250, 4), 256, 0, stream>>>(hpub, wout_bf, b_out, out,
                                                       32000, 512, partials, 250);
  lse_combine_kernel<<<1024, 64, 0, stream>>>(partials, lse, 250);
  sub_lse_kernel<<<32000, 256, 0, stream>>>(out, lse);
}